// Round 10
// baseline (1105.784 us; speedup 1.0000x reference)
//
#include <hip/hip_runtime.h>

// EPD GNN, r10. Streaming-wave MFMA GEMM with OPERAND-SWAPPED mfma:
// D' = mfma(Wfrag, Afrag) = (A@W)^T fragment -> each lane holds ROW row0+m16,
// cols nt*16+quad*4..+3 => ALL C traffic (store/ACCUM/GTERM) is per-lane
// float4 (r2..r8 measured byte-exact HBM writes with 16B/lane; r9's 4B/lane
// dword epilogue caused ~3.3-6.6x HBM amplification). W packing unchanged.
// Same streaming structure as r9: W hi/lo in LDS (64KB, fragment-ordered,
// conflict-free b128), waves grid-stride 16-row tiles, no steady barriers.

#define NN 50000
#define EE 400000
#define GG 8
#define NBLK 196    // ceil(NN/256)

typedef __attribute__((ext_vector_type(8))) short short8;
typedef __attribute__((ext_vector_type(4))) float floatx4;

__device__ __forceinline__ unsigned short f2bf(float x) {
    unsigned u = __float_as_uint(x);
    u += 0x7FFF + ((u >> 16) & 1);
    return (unsigned short)(u >> 16);
}
__device__ __forceinline__ float bf2f(unsigned short h) {
    return __uint_as_float(((unsigned)h) << 16);
}

// ---------------- CSR build ----------------
__global__ void k_count(const int* __restrict__ ei, int* __restrict__ deg) {
    int i = blockIdx.x * 256 + threadIdx.x;
    if (i < EE) atomicAdd(&deg[ei[EE + i]], 1);
}

__global__ __launch_bounds__(256) void k_scan1(const int* __restrict__ deg, int* __restrict__ ex,
                                               int* __restrict__ blksum) {
    __shared__ int s[256];
    const int t = threadIdx.x;
    int i = blockIdx.x * 256 + t;
    int v = (i < NN) ? deg[i] : 0;
    s[t] = v;
    __syncthreads();
    for (int off = 1; off < 256; off <<= 1) {
        int x = (t >= off) ? s[t - off] : 0;
        __syncthreads();
        s[t] += x;
        __syncthreads();
    }
    if (i < NN) ex[i] = s[t] - v;
    if (t == 255) blksum[blockIdx.x] = s[255];
}

__global__ __launch_bounds__(256) void k_scan2(int* __restrict__ blksum) {
    __shared__ int s[256];
    const int t = threadIdx.x;
    int v = (t < NBLK) ? blksum[t] : 0;
    s[t] = v;
    __syncthreads();
    for (int off = 1; off < 256; off <<= 1) {
        int x = (t >= off) ? s[t - off] : 0;
        __syncthreads();
        s[t] += x;
        __syncthreads();
    }
    if (t < NBLK) blksum[t] = s[t] - v;
}

__global__ void k_scan3(const int* __restrict__ ex, const int* __restrict__ blkoff,
                        int* __restrict__ row_ptr, int* __restrict__ cursor) {
    int i = blockIdx.x * 256 + threadIdx.x;
    if (i < NN) {
        int v = ex[i] + blkoff[blockIdx.x];
        row_ptr[i] = v;
        cursor[i] = v;
    }
    if (i == 0) row_ptr[NN] = EE;
}

__global__ void k_scatter(const int* __restrict__ ei, const float* __restrict__ ea,
                          int* __restrict__ cursor, int* __restrict__ src_sorted,
                          float4* __restrict__ ea_s) {
    int e = blockIdx.x * 256 + threadIdx.x;
    if (e >= EE) return;
    int s = ei[e], d = ei[EE + e];
    int p = atomicAdd(&cursor[d], 1);
    src_sorted[p] = s;
    ea_s[p] = make_float4(ea[3 * e], ea[3 * e + 1], ea[3 * e + 2], 0.f);
}

// ---------------- weight fusion: Wf = Wm2 @ Wu1[128:256], bf = bu1 + bm2 @ Wu1[128:256] ----------------
__global__ __launch_bounds__(256) void k_wfuse(const float* __restrict__ Wm2, const float* __restrict__ Wu1,
                                               float* __restrict__ Wf) {
    int idx = blockIdx.x * 256 + threadIdx.x;   // 16384
    int r = idx >> 7, c = idx & 127;
    float s = 0.f;
    for (int k = 0; k < 128; ++k) s += Wm2[r * 128 + k] * Wu1[(128 + k) * 128 + c];
    Wf[idx] = s;
}
__global__ void k_bfuse(const float* __restrict__ bm2, const float* __restrict__ Wu1,
                        const float* __restrict__ bu1, float* __restrict__ bf) {
    int c = threadIdx.x;
    float s = bu1[c];
    for (int k = 0; k < 128; ++k) s += bm2[k] * Wu1[(128 + k) * 128 + c];
    bf[c] = s;
}

// ---------------- weight packing: fragment-ordered chunks ----------------
// p = ((nt*4+k0)*64 + lane)*8 + j ; n = nt*16+(lane&15) ; k = k0*32+(lane>>4)*8+j
__global__ __launch_bounds__(256) void k_pack_all(
    const float* __restrict__ We2, const float* __restrict__ Wm1,
    const float* __restrict__ Wu1, const float* __restrict__ Wf,
    const float* __restrict__ Wu2, const float* __restrict__ Wd1,
    short* __restrict__ We2h, short* __restrict__ We2l,
    short* __restrict__ Wm1sh, short* __restrict__ Wm1sl,
    short* __restrict__ Wm1dh, short* __restrict__ Wm1dl,
    short* __restrict__ Wu1ah, short* __restrict__ Wu1al,
    short* __restrict__ Wfh, short* __restrict__ Wfl,
    short* __restrict__ Wu2h, short* __restrict__ Wu2l,
    short* __restrict__ Wd1h, short* __restrict__ Wd1l) {
    int b = blockIdx.x;
    int id = b >> 6;
    int p = (b & 63) * 256 + threadIdx.x;   // 0..16383
    const float* W;
    short *hi, *lo;
    switch (id) {
        case 0: W = We2; hi = We2h; lo = We2l; break;
        case 1: W = Wm1; hi = Wm1sh; lo = Wm1sl; break;
        case 2: W = Wm1 + 16384; hi = Wm1dh; lo = Wm1dl; break;
        case 3: W = Wu1; hi = Wu1ah; lo = Wu1al; break;
        case 4: W = Wf; hi = Wfh; lo = Wfl; break;
        case 5: W = Wu2; hi = Wu2h; lo = Wu2l; break;
        default: W = Wd1; hi = Wd1h; lo = Wd1l; break;
    }
    int j = p & 7;
    int lane = (p >> 3) & 63;
    int chunk = p >> 9;          // 0..31
    int k0 = chunk & 3, nt = chunk >> 2;
    int n = nt * 16 + (lane & 15);
    int k = k0 * 32 + (lane >> 4) * 8 + j;
    float w = W[k * 128 + n];
    unsigned short h = f2bf(w);
    hi[p] = (short)h;
    lo[p] = (short)f2bf(w - bf2f(h));
}

// ---------------- encoder layer 1 (K=8) ----------------
__global__ __launch_bounds__(256) void k_enc1(const float* __restrict__ x, const float* __restrict__ xm,
                                              const float* __restrict__ We1, const float* __restrict__ be1,
                                              float* __restrict__ t, int n) {
    __shared__ float w[8][128];
    __shared__ float b[128];
    int tid = threadIdx.x;
    for (int i = tid; i < 1024; i += 256) w[i >> 7][i & 127] = We1[i];
    if (tid < 128) b[tid] = be1[tid];
    __syncthreads();
    const int c = tid & 127, rp = tid >> 7;
    const int row0 = blockIdx.x * 32;
    for (int i = 0; i < 16; ++i) {
        int r = row0 + rp * 16 + i;
        if (r >= n) break;
        float i0 = x[r * 5 + 0], i1 = x[r * 5 + 1], i2 = x[r * 5 + 2], i3 = x[r * 5 + 3], i4 = x[r * 5 + 4];
        float m0 = xm[r * 3 + 0], m1 = xm[r * 3 + 1], m2 = xm[r * 3 + 2];
        float s = b[c] + i0 * w[0][c] + i1 * w[1][c] + i2 * w[2][c] + i3 * w[3][c] + i4 * w[4][c]
                + m0 * w[5][c] + m1 * w[6][c] + m2 * w[7][c];
        t[(size_t)r * 128 + c] = fmaxf(s, 0.f);
    }
}

// ---------------- streaming MFMA GEMM (operand-swapped, row-major C in lane) ----------------
#define SGRID 512
template <bool RELU, bool ACCUM, bool BIAS, bool GTERM, bool STATS, bool DUAL>
__global__ __launch_bounds__(256, 2) void sgemm(const float* __restrict__ A,
                                                const short* __restrict__ Whi, const short* __restrict__ Wlo,
                                                const short* __restrict__ W2hi, const short* __restrict__ W2lo,
                                                const float* __restrict__ bias, const float* __restrict__ bias2,
                                                const float* __restrict__ gt, const int* __restrict__ batch,
                                                float* __restrict__ out, float* __restrict__ out2,
                                                float* __restrict__ sum_h, int M) {
    __shared__ __align__(16) short sWh[16384];   // 32KB, fragment-ordered
    __shared__ __align__(16) short sWl[16384];   // 32KB
    const int tid = threadIdx.x;
    const int wave = tid >> 6, lane = tid & 63;
    const int m16 = lane & 15, quad = lane >> 4;
    const int ntiles = (M + 15) >> 4;

    auto copyW = [&](const short* gh, const short* gl) {
        const float4* srcH = (const float4*)gh;
        const float4* srcL = (const float4*)gl;
        float4* dH = (float4*)sWh;
        float4* dL = (float4*)sWl;
#pragma unroll
        for (int u = 0; u < 8; ++u) {
            int i = tid + u * 256;
            dH[i] = srcH[i];
            dL[i] = srcL[i];
        }
    };

    copyW(Whi, Wlo);
    __syncthreads();

    // per-lane bias float4 for cols nt*16+quad*4
    float4 bcol[8];
    if (BIAS && !DUAL) {
#pragma unroll
        for (int nt = 0; nt < 8; ++nt) bcol[nt] = *(const float4*)(bias + nt * 16 + quad * 4);
    }

    for (int pass = 0; pass < (DUAL ? 2 : 1); ++pass) {
        if (DUAL && pass == 1) {
            __syncthreads();
            copyW(W2hi, W2lo);
            __syncthreads();
#pragma unroll
            for (int nt = 0; nt < 8; ++nt) bcol[nt] = *(const float4*)(bias2 + nt * 16 + quad * 4);
        }
        float* outp = (DUAL && pass == 1) ? out2 : out;

        for (int tile = blockIdx.x * 4 + wave; tile < ntiles; tile += SGRID * 4) {
            const int row0 = tile * 16;
            int r = row0 + m16;
            if (r >= M) r = M - 1;          // M=50000 is 16-divisible; safety only
            const float* Ap = A + (size_t)r * 128;
            float4 av[8];
#pragma unroll
            for (int k0 = 0; k0 < 4; ++k0) {
                av[k0 * 2 + 0] = *(const float4*)(Ap + k0 * 32 + quad * 8);
                av[k0 * 2 + 1] = *(const float4*)(Ap + k0 * 32 + quad * 8 + 4);
            }
            floatx4 acc[8];
#pragma unroll
            for (int nt = 0; nt < 8; ++nt) acc[nt] = (floatx4)0.f;
#pragma unroll
            for (int k0 = 0; k0 < 4; ++k0) {
                float tv[8] = {av[k0 * 2].x, av[k0 * 2].y, av[k0 * 2].z, av[k0 * 2].w,
                               av[k0 * 2 + 1].x, av[k0 * 2 + 1].y, av[k0 * 2 + 1].z, av[k0 * 2 + 1].w};
                short8 ah, al;
#pragma unroll
                for (int j = 0; j < 8; ++j) {
                    unsigned short hh = f2bf(tv[j]);
                    ah[j] = (short)hh;
                    al[j] = (short)f2bf(tv[j] - bf2f(hh));
                }
#pragma unroll
                for (int nt = 0; nt < 8; ++nt) {
                    const int base = (((nt << 2) | k0) << 9) + (lane << 3);
                    short8 bh = *(const short8*)&sWh[base];
                    short8 bl = *(const short8*)&sWl[base];
                    // SWAPPED operands: D' = Wfrag x Afrag = (A@W)^T fragment
                    acc[nt] = __builtin_amdgcn_mfma_f32_16x16x32_bf16(bh, ah, acc[nt], 0, 0, 0);
                    acc[nt] = __builtin_amdgcn_mfma_f32_16x16x32_bf16(bl, ah, acc[nt], 0, 0, 0);
                    acc[nt] = __builtin_amdgcn_mfma_f32_16x16x32_bf16(bh, al, acc[nt], 0, 0, 0);
                }
            }
            // epilogue: lane owns row r, cols nt*16+quad*4..+3 -> all float4
            float* orow = outp + (size_t)r * 128 + quad * 4;
            float o[8][4];
#pragma unroll
            for (int nt = 0; nt < 8; ++nt)
#pragma unroll
                for (int i = 0; i < 4; ++i) o[nt][i] = acc[nt][i];
            if (BIAS || (DUAL && pass == 1)) {
                if (!DUAL || pass == 1) {
#pragma unroll
                    for (int nt = 0; nt < 8; ++nt) {
                        o[nt][0] += bcol[nt].x; o[nt][1] += bcol[nt].y;
                        o[nt][2] += bcol[nt].z; o[nt][3] += bcol[nt].w;
                    }
                }
            }
            if (GTERM) {
                const float* gp = gt + batch[r] * 128 + quad * 4;
#pragma unroll
                for (int nt = 0; nt < 8; ++nt) {
                    float4 gv = *(const float4*)(gp + nt * 16);
                    o[nt][0] += gv.x; o[nt][1] += gv.y; o[nt][2] += gv.z; o[nt][3] += gv.w;
                }
            }
            if (ACCUM) {
#pragma unroll
                for (int nt = 0; nt < 8; ++nt) {
                    float4 ev = *(const float4*)(orow + nt * 16);
                    o[nt][0] += ev.x; o[nt][1] += ev.y; o[nt][2] += ev.z; o[nt][3] += ev.w;
                }
            }
            if (RELU) {
#pragma unroll
                for (int nt = 0; nt < 8; ++nt)
#pragma unroll
                    for (int i = 0; i < 4; ++i) o[nt][i] = fmaxf(o[nt][i], 0.f);
            }
#pragma unroll
            for (int nt = 0; nt < 8; ++nt)
                *(float4*)(orow + nt * 16) = make_float4(o[nt][0], o[nt][1], o[nt][2], o[nt][3]);
            if (STATS) {
                int rhi = (row0 + 15 < M) ? row0 + 15 : M - 1;
                int g0 = batch[row0];
                if (g0 == batch[rhi]) {
                    // reduce over the 16 rows (m16 lanes) via shfl_xor
#pragma unroll
                    for (int nt = 0; nt < 8; ++nt) {
                        float4 v = make_float4(o[nt][0], o[nt][1], o[nt][2], o[nt][3]);
#pragma unroll
                        for (int off = 1; off < 16; off <<= 1) {
                            v.x += __shfl_xor(v.x, off);
                            v.y += __shfl_xor(v.y, off);
                            v.z += __shfl_xor(v.z, off);
                            v.w += __shfl_xor(v.w, off);
                        }
                        if (m16 == 0) {
                            float* sp = &sum_h[g0 * 128 + nt * 16 + quad * 4];
                            atomicAdd(sp + 0, v.x);
                            atomicAdd(sp + 1, v.y);
                            atomicAdd(sp + 2, v.z);
                            atomicAdd(sp + 3, v.w);
                        }
                    }
                } else {
                    int g = batch[r];
#pragma unroll
                    for (int nt = 0; nt < 8; ++nt) {
                        float* sp = &sum_h[g * 128 + nt * 16 + quad * 4];
                        atomicAdd(sp + 0, o[nt][0]);
                        atomicAdd(sp + 1, o[nt][1]);
                        atomicAdd(sp + 2, o[nt][2]);
                        atomicAdd(sp + 3, o[nt][3]);
                    }
                }
            }
        }
    }
}

// ---------------- edge aggregation: one wave per destination node ----------------
__global__ __launch_bounds__(256) void k_edge_agg(const float* __restrict__ Ps, const float* __restrict__ Pd,
                                                  const int* __restrict__ row_ptr, const int* __restrict__ src_sorted,
                                                  const float4* __restrict__ ea_s, const float* __restrict__ Wm1,
                                                  float* __restrict__ accm) {
    const int lane = threadIdx.x & 63;
    const int d = blockIdx.x * 4 + (threadIdx.x >> 6);
    const int c = lane * 2;
    const float2 w0 = *(const float2*)&Wm1[256 * 128 + c];
    const float2 w1 = *(const float2*)&Wm1[257 * 128 + c];
    const float2 w2 = *(const float2*)&Wm1[258 * 128 + c];
    const float2 pd = *(const float2*)&Pd[(size_t)d * 128 + c];
    const int beg = row_ptr[d], end = row_ptr[d + 1];
    const float2 sv = *(const float2*)&Ps[(size_t)d * 128 + c];
    float ax = fmaxf(sv.x + pd.x, 0.f);
    float ay = fmaxf(sv.y + pd.y, 0.f);
    int k = beg;
    for (; k + 3 < end; k += 4) {
        int s0 = src_sorted[k], s1 = src_sorted[k + 1], s2 = src_sorted[k + 2], s3 = src_sorted[k + 3];
        float4 e0 = ea_s[k], e1 = ea_s[k + 1], e2 = ea_s[k + 2], e3 = ea_s[k + 3];
        float2 pa = *(const float2*)&Ps[(size_t)s0 * 128 + c];
        float2 pb = *(const float2*)&Ps[(size_t)s1 * 128 + c];
        float2 pc = *(const float2*)&Ps[(size_t)s2 * 128 + c];
        float2 pe = *(const float2*)&Ps[(size_t)s3 * 128 + c];
        ax += fmaxf(pa.x + pd.x + e0.x * w0.x + e0.y * w1.x + e0.z * w2.x, 0.f)
            + fmaxf(pb.x + pd.x + e1.x * w0.x + e1.y * w1.x + e1.z * w2.x, 0.f)
            + fmaxf(pc.x + pd.x + e2.x * w0.x + e2.y * w1.x + e2.z * w2.x, 0.f)
            + fmaxf(pe.x + pd.x + e3.x * w0.x + e3.y * w1.x + e3.z * w2.x, 0.f);
        ay += fmaxf(pa.y + pd.y + e0.x * w0.y + e0.y * w1.y + e0.z * w2.y, 0.f)
            + fmaxf(pb.y + pd.y + e1.x * w0.y + e1.y * w1.y + e1.z * w2.y, 0.f)
            + fmaxf(pc.y + pd.y + e2.x * w0.y + e2.y * w1.y + e2.z * w2.y, 0.f)
            + fmaxf(pe.y + pd.y + e3.x * w0.y + e3.y * w1.y + e3.z * w2.y, 0.f);
    }
    for (; k < end; ++k) {
        int s0 = src_sorted[k];
        float4 e0 = ea_s[k];
        float2 pa = *(const float2*)&Ps[(size_t)s0 * 128 + c];
        ax += fmaxf(pa.x + pd.x + e0.x * w0.x + e0.y * w1.x + e0.z * w2.x, 0.f);
        ay += fmaxf(pa.y + pd.y + e0.x * w0.y + e0.y * w1.y + e0.z * w2.y, 0.f);
    }
    float inv = 1.f / (float)(end - beg + 1);
    *(float2*)&accm[(size_t)d * 128 + c] = make_float2(ax * inv, ay * inv);
}

// ---------------- encoder per-graph stats (once) ----------------
__global__ __launch_bounds__(256) void k_stats_bc(const float* __restrict__ h, const float* __restrict__ xm,
                                                  const int* __restrict__ batch, float* __restrict__ sum_h,
                                                  float* __restrict__ sum_hbc, float* __restrict__ cnt_node,
                                                  float* __restrict__ cnt_bc) {
    __shared__ float sred[8][128];
    __shared__ float scn[8], scb[8];
    const int t = threadIdx.x;
    const int c4 = (t & 31) * 4;
    const int rsub = t >> 5;   // 0..7
    const int row0 = blockIdx.x * 64;
    int rlo = (row0 < NN) ? row0 : (NN - 1);
    int rhi = (row0 + 63 < NN) ? row0 + 63 : (NN - 1);
    const int gl = batch[rlo];
    const bool uni = (gl == batch[rhi]);
    float4 s = make_float4(0.f, 0.f, 0.f, 0.f), sb = make_float4(0.f, 0.f, 0.f, 0.f);
    float cn = 0.f, cb = 0.f;
#pragma unroll
    for (int ii = 0; ii < 8; ++ii) {
        int r = row0 + ii * 8 + rsub;
        if (r >= NN) continue;
        float4 v = *(const float4*)(h + (size_t)r * 128 + c4);
        float bc = xm[r * 3 + 2];
        if (uni) {
            s.x += v.x; s.y += v.y; s.z += v.z; s.w += v.w;
            sb.x += v.x * bc; sb.y += v.y * bc; sb.z += v.z * bc; sb.w += v.w * bc;
            if ((t & 31) == 0) { cn += 1.f; cb += bc; }
        } else {
            int g = batch[r];
            atomicAdd(&sum_h[g * 128 + c4 + 0], v.x);
            atomicAdd(&sum_h[g * 128 + c4 + 1], v.y);
            atomicAdd(&sum_h[g * 128 + c4 + 2], v.z);
            atomicAdd(&sum_h[g * 128 + c4 + 3], v.w);
            atomicAdd(&sum_hbc[g * 128 + c4 + 0], v.x * bc);
            atomicAdd(&sum_hbc[g * 128 + c4 + 1], v.y * bc);
            atomicAdd(&sum_hbc[g * 128 + c4 + 2], v.z * bc);
            atomicAdd(&sum_hbc[g * 128 + c4 + 3], v.w * bc);
            if ((t & 31) == 0) {
                atomicAdd(&cnt_node[g], 1.f);
                atomicAdd(&cnt_bc[g], bc);
            }
        }
    }
    if (!uni) return;
    *(float4*)&sred[rsub][c4] = s;
    __syncthreads();
    if (t < 128) {
        float tot = 0.f;
#pragma unroll
        for (int q = 0; q < 8; ++q) tot += sred[q][t];
        atomicAdd(&sum_h[gl * 128 + t], tot);
    }
    __syncthreads();
    *(float4*)&sred[rsub][c4] = sb;
    if ((t & 31) == 0) { scn[rsub] = cn; scb[rsub] = cb; }
    __syncthreads();
    if (t < 128) {
        float tot = 0.f;
#pragma unroll
        for (int q = 0; q < 8; ++q) tot += sred[q][t];
        atomicAdd(&sum_hbc[gl * 128 + t], tot);
    }
    if (t == 0) {
        float a = 0.f, b = 0.f;
#pragma unroll
        for (int q = 0; q < 8; ++q) { a += scn[q]; b += scb[q]; }
        atomicAdd(&cnt_node[gl], a);
        atomicAdd(&cnt_bc[gl], b);
    }
}

// gterm[g] = mean_h[g] @ Wu1[256:384] + mean_hbc[g] @ Wu1[384:512]
__global__ __launch_bounds__(128) void k_gterm(const float* __restrict__ sum_h, const float* __restrict__ sum_hbc,
                                               const float* __restrict__ cnt_node, const float* __restrict__ cnt_bc,
                                               const float* __restrict__ Wu1, float* __restrict__ gt) {
    const int g = blockIdx.x;
    const int c = threadIdx.x;
    __shared__ float sg[128], sb[128];
    const float invn = 1.f / fmaxf(cnt_node[g], 1.f);
    const float invb = 1.f / fmaxf(cnt_bc[g], 1.f);
    sg[c] = sum_h[g * 128 + c] * invn;
    sb[c] = sum_hbc[g * 128 + c] * invb;
    __syncthreads();
    float s = 0.f;
    for (int k = 0; k < 128; ++k) s += sg[k] * Wu1[(256 + k) * 128 + c];
    for (int k = 0; k < 128; ++k) s += sb[k] * Wu1[(384 + k) * 128 + c];
    gt[g * 128 + c] = s;
}

// ---------------- decoder layer 2 (128 -> 3), one wave per row ----------------
__global__ __launch_bounds__(256) void k_dec2(const float* __restrict__ t, const float* __restrict__ Wd2,
                                              const float* __restrict__ bd2, float* __restrict__ out, int n) {
    const int lane = threadIdx.x & 63;
    const int r = blockIdx.x * 4 + (threadIdx.x >> 6);
    if (r >= n) return;
    float p0 = 0.f, p1 = 0.f, p2 = 0.f;
    for (int k = lane; k < 128; k += 64) {
        float tv = t[(size_t)r * 128 + k];
        p0 += tv * Wd2[k * 3 + 0];
        p1 += tv * Wd2[k * 3 + 1];
        p2 += tv * Wd2[k * 3 + 2];
    }
    for (int off = 32; off; off >>= 1) {
        p0 += __shfl_down(p0, off);
        p1 += __shfl_down(p1, off);
        p2 += __shfl_down(p2, off);
    }
    if (lane == 0) {
        out[r * 3 + 0] = p0 + bd2[0];
        out[r * 3 + 1] = p1 + bd2[1];
        out[r * 3 + 2] = p2 + bd2[2];
    }
}

extern "C" void kernel_launch(void* const* d_in, const int* in_sizes, int n_in,
                              void* d_out, int out_size, void* d_ws, size_t ws_size,
                              hipStream_t stream) {
    const float* x = (const float*)d_in[0];
    const float* x_mask = (const float*)d_in[1];
    const float* edge_attr = (const float*)d_in[2];
    const float* W_e1 = (const float*)d_in[4];
    const float* b_e1 = (const float*)d_in[5];
    const float* W_e2 = (const float*)d_in[6];
    const float* b_e2 = (const float*)d_in[7];
    const float* W_m1 = (const float*)d_in[8];
    const float* b_m1 = (const float*)d_in[9];
    const float* W_m2 = (const float*)d_in[10];
    const float* b_m2 = (const float*)d_in[11];
    const float* W_u1 = (const float*)d_in[12];
    const float* b_u1 = (const float*)d_in[13];
    const float* W_u2 = (const float*)d_in[14];
    const float* b_u2 = (const float*)d_in[15];
    const float* W_d1 = (const float*)d_in[16];
    const float* b_d1 = (const float*)d_in[17];
    const float* W_d2 = (const float*)d_in[18];
    const float* b_d2 = (const float*)d_in[19];
    const int* edge_index = (const int*)d_in[20];
    const int* batch = (const int*)d_in[21];
    float* out = (float*)d_out;

    char* wp = (char*)d_ws;
    auto carve = [&](size_t bytes) {
        char* r = wp;
        wp += (bytes + 255) & ~(size_t)255;
        return r;
    };
    float* h = (float*)carve(sizeof(float) * (size_t)NN * 128);
    float* Ps = (float*)carve(sizeof(float) * (size_t)NN * 128);
    float* Pd = (float*)carve(sizeof(float) * (size_t)NN * 128);
    float* accm = (float*)carve(sizeof(float) * (size_t)NN * 128);
    float4* ea_s = (float4*)carve(sizeof(float4) * (size_t)EE);
    float* stats = (float*)carve(sizeof(float) * 4096);
    float* sum_h = stats;             // 1024
    float* sum_hbc = stats + 1024;    // 1024
    float* cnt_node = stats + 2048;   // 8
    float* cnt_bc = stats + 2056;     // 8
    float* gterm = stats + 2304;      // 1024
    float* bfused = stats + 3328;     // 128
    int* deg = (int*)carve(sizeof(int) * NN);
    int* row_ptr = (int*)carve(sizeof(int) * (NN + 1));
    int* cursor = (int*)carve(sizeof(int) * NN);
    int* src_sorted = (int*)carve(sizeof(int) * EE);
    int* exbuf = (int*)carve(sizeof(int) * NN);
    int* blksum = (int*)carve(sizeof(int) * 256);
    float* Wf = (float*)carve(sizeof(float) * 16384);
    // packed weights (bf16 hi/lo, fragment-ordered, all 128x128)
    short* We2h = (short*)carve(sizeof(short) * 16384);
    short* We2l = (short*)carve(sizeof(short) * 16384);
    short* Wm1sh = (short*)carve(sizeof(short) * 16384);
    short* Wm1sl = (short*)carve(sizeof(short) * 16384);
    short* Wm1dh = (short*)carve(sizeof(short) * 16384);
    short* Wm1dl = (short*)carve(sizeof(short) * 16384);
    short* Wu1ah = (short*)carve(sizeof(short) * 16384);
    short* Wu1al = (short*)carve(sizeof(short) * 16384);
    short* Wfh = (short*)carve(sizeof(short) * 16384);
    short* Wfl = (short*)carve(sizeof(short) * 16384);
    short* Wu2h = (short*)carve(sizeof(short) * 16384);
    short* Wu2l = (short*)carve(sizeof(short) * 16384);
    short* Wd1h = (short*)carve(sizeof(short) * 16384);
    short* Wd1l = (short*)carve(sizeof(short) * 16384);

    const dim3 b256(256);
    const int gE256 = (EE + 255) / 256;

    hipMemsetAsync(deg, 0, sizeof(int) * NN, stream);
    hipMemsetAsync(stats, 0, sizeof(float) * 2064, stream);
    // fused weights + packing
    k_wfuse<<<64, b256, 0, stream>>>(W_m2, W_u1, Wf);
    k_bfuse<<<1, 128, 0, stream>>>(b_m2, W_u1, b_u1, bfused);
    k_pack_all<<<448, b256, 0, stream>>>(W_e2, W_m1, W_u1, Wf, W_u2, W_d1,
                                         We2h, We2l, Wm1sh, Wm1sl, Wm1dh, Wm1dl,
                                         Wu1ah, Wu1al, Wfh, Wfl, Wu2h, Wu2l, Wd1h, Wd1l);
    // CSR
    k_count<<<gE256, b256, 0, stream>>>(edge_index, deg);
    k_scan1<<<NBLK, b256, 0, stream>>>(deg, exbuf, blksum);
    k_scan2<<<1, b256, 0, stream>>>(blksum);
    k_scan3<<<NBLK, b256, 0, stream>>>(exbuf, blksum, row_ptr, cursor);
    k_scatter<<<gE256, b256, 0, stream>>>(edge_index, edge_attr, cursor, src_sorted, ea_s);
    // encoder
    k_enc1<<<(NN + 31) / 32, b256, 0, stream>>>(x, x_mask, W_e1, b_e1, accm, NN);
    sgemm<false, false, true, false, false, false><<<SGRID, b256, 0, stream>>>(
        accm, We2h, We2l, nullptr, nullptr, b_e2, nullptr, nullptr, nullptr, h, nullptr, nullptr, NN);
    // per-graph stats (once)
    k_stats_bc<<<(NN + 63) / 64, b256, 0, stream>>>(h, x_mask, batch, sum_h, sum_hbc, cnt_node, cnt_bc);

    for (int rep = 0; rep < 3; ++rep) {
        k_gterm<<<GG, 128, 0, stream>>>(sum_h, sum_hbc, cnt_node, cnt_bc, W_u1, gterm);
        // Ps = h@Wm1s ; Pd = h@Wm1d + b_m1  (two passes, one kernel)
        sgemm<false, false, false, false, false, true><<<SGRID, b256, 0, stream>>>(
            h, Wm1sh, Wm1sl, Wm1dh, Wm1dl, nullptr, b_m1, nullptr, nullptr, Ps, Pd, nullptr, NN);
        k_edge_agg<<<NN / 4, b256, 0, stream>>>(Ps, Pd, row_ptr, src_sorted, ea_s, W_m1, accm);
        // tmp = h@Wu1a + gterm[batch] + bfused -> Pd
        sgemm<false, false, true, true, false, false><<<SGRID, b256, 0, stream>>>(
            h, Wu1ah, Wu1al, nullptr, nullptr, bfused, nullptr, gterm, batch, Pd, nullptr, nullptr, NN);
        // pre = relu(tmp + accm@Wf) -> Pd (ACCUM)
        sgemm<true, true, false, false, false, false><<<SGRID, b256, 0, stream>>>(
            accm, Wfh, Wfl, nullptr, nullptr, nullptr, nullptr, nullptr, nullptr, Pd, nullptr, nullptr, NN);
        // h += pre@Wu2 + bu2 (+stats for next rep)
        if (rep < 2) {
            hipMemsetAsync(sum_h, 0, sizeof(float) * 1024, stream);
            sgemm<false, true, true, false, true, false><<<SGRID, b256, 0, stream>>>(
                Pd, Wu2h, Wu2l, nullptr, nullptr, b_u2, nullptr, nullptr, batch, h, nullptr, sum_h, NN);
        } else {
            sgemm<false, true, true, false, false, false><<<SGRID, b256, 0, stream>>>(
                Pd, Wu2h, Wu2l, nullptr, nullptr, b_u2, nullptr, nullptr, batch, h, nullptr, nullptr, NN);
        }
    }
    // decoder
    sgemm<true, false, true, false, false, false><<<SGRID, b256, 0, stream>>>(
        h, Wd1h, Wd1l, nullptr, nullptr, b_d1, nullptr, nullptr, nullptr, accm, nullptr, nullptr, NN);
    k_dec2<<<NN / 4, b256, 0, stream>>>(accm, W_d2, b_d2, out, NN);
}

// Round 11
// 746.458 us; speedup vs baseline: 1.4814x; 1.4814x over previous
//
#include <hip/hip_runtime.h>

// EPD GNN, r11. Streaming MFMA GEMM, swapped-operand (row-major C in lane,
// verified r10: byte-exact HBM traffic). New: 2 tiles per wave interleaved in
// one peeled body (all A/ACCUM loads batched up-front, 6 MFMA per LDS frag),
// A kept in registers as bf16 hi/lo across passes. TRIPLE kernel computes
// Ps, Pd, tmp=h@Wu1a+gt+bf in ONE dispatch (3 W restages, A read once).

#define NN 50000
#define EE 400000
#define GG 8
#define NBLK 196    // ceil(NN/256)
#define SGRID 512   // 2 blocks/CU, all resident; 2048 waves over 3125 tiles

typedef __attribute__((ext_vector_type(8))) short short8;
typedef __attribute__((ext_vector_type(4))) float floatx4;

__device__ __forceinline__ unsigned short f2bf(float x) {
    unsigned u = __float_as_uint(x);
    u += 0x7FFF + ((u >> 16) & 1);
    return (unsigned short)(u >> 16);
}
__device__ __forceinline__ float bf2f(unsigned short h) {
    return __uint_as_float(((unsigned)h) << 16);
}
__device__ __forceinline__ void cvt8(const float* v, short8& hi, short8& lo) {
#pragma unroll
    for (int j = 0; j < 8; ++j) {
        unsigned short h = f2bf(v[j]);
        hi[j] = (short)h;
        lo[j] = (short)f2bf(v[j] - bf2f(h));
    }
}

// ---------------- CSR build ----------------
__global__ void k_count(const int* __restrict__ ei, int* __restrict__ deg) {
    int i = blockIdx.x * 256 + threadIdx.x;
    if (i < EE) atomicAdd(&deg[ei[EE + i]], 1);
}

__global__ __launch_bounds__(256) void k_scan1(const int* __restrict__ deg, int* __restrict__ ex,
                                               int* __restrict__ blksum) {
    __shared__ int s[256];
    const int t = threadIdx.x;
    int i = blockIdx.x * 256 + t;
    int v = (i < NN) ? deg[i] : 0;
    s[t] = v;
    __syncthreads();
    for (int off = 1; off < 256; off <<= 1) {
        int x = (t >= off) ? s[t - off] : 0;
        __syncthreads();
        s[t] += x;
        __syncthreads();
    }
    if (i < NN) ex[i] = s[t] - v;
    if (t == 255) blksum[blockIdx.x] = s[255];
}

__global__ __launch_bounds__(256) void k_scan2(int* __restrict__ blksum) {
    __shared__ int s[256];
    const int t = threadIdx.x;
    int v = (t < NBLK) ? blksum[t] : 0;
    s[t] = v;
    __syncthreads();
    for (int off = 1; off < 256; off <<= 1) {
        int x = (t >= off) ? s[t - off] : 0;
        __syncthreads();
        s[t] += x;
        __syncthreads();
    }
    if (t < NBLK) blksum[t] = s[t] - v;
}

__global__ void k_scan3(const int* __restrict__ ex, const int* __restrict__ blkoff,
                        int* __restrict__ row_ptr, int* __restrict__ cursor) {
    int i = blockIdx.x * 256 + threadIdx.x;
    if (i < NN) {
        int v = ex[i] + blkoff[blockIdx.x];
        row_ptr[i] = v;
        cursor[i] = v;
    }
    if (i == 0) row_ptr[NN] = EE;
}

__global__ void k_scatter(const int* __restrict__ ei, const float* __restrict__ ea,
                          int* __restrict__ cursor, int* __restrict__ src_sorted,
                          float4* __restrict__ ea_s) {
    int e = blockIdx.x * 256 + threadIdx.x;
    if (e >= EE) return;
    int s = ei[e], d = ei[EE + e];
    int p = atomicAdd(&cursor[d], 1);
    src_sorted[p] = s;
    ea_s[p] = make_float4(ea[3 * e], ea[3 * e + 1], ea[3 * e + 2], 0.f);
}

// ---------------- weight fusion: Wf = Wm2 @ Wu1[128:256], bf = bu1 + bm2 @ Wu1[128:256] ----------------
__global__ __launch_bounds__(256) void k_wfuse(const float* __restrict__ Wm2, const float* __restrict__ Wu1,
                                               float* __restrict__ Wf) {
    int idx = blockIdx.x * 256 + threadIdx.x;   // 16384
    int r = idx >> 7, c = idx & 127;
    float s = 0.f;
    for (int k = 0; k < 128; ++k) s += Wm2[r * 128 + k] * Wu1[(128 + k) * 128 + c];
    Wf[idx] = s;
}
__global__ void k_bfuse(const float* __restrict__ bm2, const float* __restrict__ Wu1,
                        const float* __restrict__ bu1, float* __restrict__ bf) {
    int c = threadIdx.x;
    float s = bu1[c];
    for (int k = 0; k < 128; ++k) s += bm2[k] * Wu1[(128 + k) * 128 + c];
    bf[c] = s;
}

// ---------------- weight packing: fragment-ordered chunks ----------------
// p = ((nt*4+k0)*64 + lane)*8 + j ; n = nt*16+(lane&15) ; k = k0*32+(lane>>4)*8+j
__global__ __launch_bounds__(256) void k_pack_all(
    const float* __restrict__ We2, const float* __restrict__ Wm1,
    const float* __restrict__ Wu1, const float* __restrict__ Wf,
    const float* __restrict__ Wu2, const float* __restrict__ Wd1,
    short* __restrict__ We2h, short* __restrict__ We2l,
    short* __restrict__ Wm1sh, short* __restrict__ Wm1sl,
    short* __restrict__ Wm1dh, short* __restrict__ Wm1dl,
    short* __restrict__ Wu1ah, short* __restrict__ Wu1al,
    short* __restrict__ Wfh, short* __restrict__ Wfl,
    short* __restrict__ Wu2h, short* __restrict__ Wu2l,
    short* __restrict__ Wd1h, short* __restrict__ Wd1l) {
    int b = blockIdx.x;
    int id = b >> 6;
    int p = (b & 63) * 256 + threadIdx.x;   // 0..16383
    const float* W;
    short *hi, *lo;
    switch (id) {
        case 0: W = We2; hi = We2h; lo = We2l; break;
        case 1: W = Wm1; hi = Wm1sh; lo = Wm1sl; break;
        case 2: W = Wm1 + 16384; hi = Wm1dh; lo = Wm1dl; break;
        case 3: W = Wu1; hi = Wu1ah; lo = Wu1al; break;
        case 4: W = Wf; hi = Wfh; lo = Wfl; break;
        case 5: W = Wu2; hi = Wu2h; lo = Wu2l; break;
        default: W = Wd1; hi = Wd1h; lo = Wd1l; break;
    }
    int j = p & 7;
    int lane = (p >> 3) & 63;
    int chunk = p >> 9;          // 0..31
    int k0 = chunk & 3, nt = chunk >> 2;
    int n = nt * 16 + (lane & 15);
    int k = k0 * 32 + (lane >> 4) * 8 + j;
    float w = W[k * 128 + n];
    unsigned short h = f2bf(w);
    hi[p] = (short)h;
    lo[p] = (short)f2bf(w - bf2f(h));
}

// ---------------- encoder layer 1 (K=8) ----------------
__global__ __launch_bounds__(256) void k_enc1(const float* __restrict__ x, const float* __restrict__ xm,
                                              const float* __restrict__ We1, const float* __restrict__ be1,
                                              float* __restrict__ t, int n) {
    __shared__ float w[8][128];
    __shared__ float b[128];
    int tid = threadIdx.x;
    for (int i = tid; i < 1024; i += 256) w[i >> 7][i & 127] = We1[i];
    if (tid < 128) b[tid] = be1[tid];
    __syncthreads();
    const int c = tid & 127, rp = tid >> 7;
    const int row0 = blockIdx.x * 32;
    for (int i = 0; i < 16; ++i) {
        int r = row0 + rp * 16 + i;
        if (r >= n) break;
        float i0 = x[r * 5 + 0], i1 = x[r * 5 + 1], i2 = x[r * 5 + 2], i3 = x[r * 5 + 3], i4 = x[r * 5 + 4];
        float m0 = xm[r * 3 + 0], m1 = xm[r * 3 + 1], m2 = xm[r * 3 + 2];
        float s = b[c] + i0 * w[0][c] + i1 * w[1][c] + i2 * w[2][c] + i3 * w[3][c] + i4 * w[4][c]
                + m0 * w[5][c] + m1 * w[6][c] + m2 * w[7][c];
        t[(size_t)r * 128 + c] = fmaxf(s, 0.f);
    }
}

// ---------------- streaming MFMA GEMM: 2 tiles/wave peeled+interleaved ----------------
// TRIPLE: out1=A@W1, out2=A@W2+bias2, out3=A@W3+gterm[batch]+bf3 (A read once).
// else: out1 = op(A@W1 [+bias1] [+out1(ACCUM)]) [+STATS col-sums].
template <bool RELU, bool ACCUM, bool BIAS, bool STATS, bool TRIPLE>
__global__ __launch_bounds__(256, 2) void sgemm(
    const float* __restrict__ A,
    const short* __restrict__ W1h, const short* __restrict__ W1l,
    const short* __restrict__ W2h, const short* __restrict__ W2l,
    const short* __restrict__ W3h, const short* __restrict__ W3l,
    const float* __restrict__ bias1, const float* __restrict__ bias2,
    const float* __restrict__ gt, const float* __restrict__ bf3,
    const int* __restrict__ batch,
    float* __restrict__ out1, float* __restrict__ out2, float* __restrict__ out3,
    float* __restrict__ sum_h, int M) {
    __shared__ __align__(16) short sWh[16384];
    __shared__ __align__(16) short sWl[16384];
    const int tid = threadIdx.x;
    const int wave = tid >> 6, lane = tid & 63;
    const int m16 = lane & 15, quad = lane >> 4;
    const int ntiles = (M + 15) >> 4;        // 3125 for M=50000
    const int t0 = blockIdx.x * 4 + wave;    // 0..2047, always < ntiles
    const int t1 = t0 + SGRID * 4;
    const bool h1 = (t1 < ntiles);
    const int r0 = t0 * 16 + m16;
    const int r1 = (h1 ? t1 * 16 : 0) + m16;

    auto copyW = [&](const short* gh, const short* gl) {
        const float4* sH = (const float4*)gh;
        const float4* sL = (const float4*)gl;
        float4* dH = (float4*)sWh;
        float4* dL = (float4*)sWl;
#pragma unroll
        for (int u = 0; u < 8; ++u) {
            int i = tid + u * 256;
            dH[i] = sH[i];
            dL[i] = sL[i];
        }
    };

    // ---- batch ALL independent global loads up front ----
    const float* Ap0 = A + (size_t)r0 * 128 + quad * 8;
    const float* Ap1 = A + (size_t)r1 * 128 + quad * 8;
    float4 a0[8], a1[8];
#pragma unroll
    for (int k0 = 0; k0 < 4; ++k0) {
        a0[k0 * 2 + 0] = *(const float4*)(Ap0 + k0 * 32);
        a0[k0 * 2 + 1] = *(const float4*)(Ap0 + k0 * 32 + 4);
    }
#pragma unroll
    for (int k0 = 0; k0 < 4; ++k0) {
        a1[k0 * 2 + 0] = *(const float4*)(Ap1 + k0 * 32);
        a1[k0 * 2 + 1] = *(const float4*)(Ap1 + k0 * 32 + 4);
    }
    float4 e0[8], e1[8];
    if (ACCUM) {
        const float* O0 = out1 + (size_t)r0 * 128 + quad * 4;
        const float* O1 = out1 + (size_t)r1 * 128 + quad * 4;
#pragma unroll
        for (int nt = 0; nt < 8; ++nt) e0[nt] = *(const float4*)(O0 + nt * 16);
#pragma unroll
        for (int nt = 0; nt < 8; ++nt) e1[nt] = *(const float4*)(O1 + nt * 16);
    }
    int g0 = 0, g1 = 0;
    if (TRIPLE || STATS) {
        g0 = batch[r0];
        g1 = batch[r1];
    }

    copyW(W1h, W1l);
    __syncthreads();

    // ---- convert A once, keep bf16 hi/lo in registers for all passes ----
    short8 ah0[4], al0[4], ah1[4], al1[4];
#pragma unroll
    for (int k0 = 0; k0 < 4; ++k0) {
        float v[8] = {a0[k0 * 2].x, a0[k0 * 2].y, a0[k0 * 2].z, a0[k0 * 2].w,
                      a0[k0 * 2 + 1].x, a0[k0 * 2 + 1].y, a0[k0 * 2 + 1].z, a0[k0 * 2 + 1].w};
        cvt8(v, ah0[k0], al0[k0]);
    }
#pragma unroll
    for (int k0 = 0; k0 < 4; ++k0) {
        float v[8] = {a1[k0 * 2].x, a1[k0 * 2].y, a1[k0 * 2].z, a1[k0 * 2].w,
                      a1[k0 * 2 + 1].x, a1[k0 * 2 + 1].y, a1[k0 * 2 + 1].z, a1[k0 * 2 + 1].w};
        cvt8(v, ah1[k0], al1[k0]);
    }

    floatx4 acc0[8], acc1[8];
    auto mmacc = [&]() {
#pragma unroll
        for (int nt = 0; nt < 8; ++nt) {
            acc0[nt] = (floatx4)0.f;
            acc1[nt] = (floatx4)0.f;
        }
#pragma unroll
        for (int k0 = 0; k0 < 4; ++k0) {
#pragma unroll
            for (int nt = 0; nt < 8; ++nt) {
                const int base = (((nt << 2) | k0) << 9) + (lane << 3);
                short8 bh = *(const short8*)&sWh[base];
                short8 bl = *(const short8*)&sWl[base];
                acc0[nt] = __builtin_amdgcn_mfma_f32_16x16x32_bf16(bh, ah0[k0], acc0[nt], 0, 0, 0);
                acc0[nt] = __builtin_amdgcn_mfma_f32_16x16x32_bf16(bl, ah0[k0], acc0[nt], 0, 0, 0);
                acc0[nt] = __builtin_amdgcn_mfma_f32_16x16x32_bf16(bh, al0[k0], acc0[nt], 0, 0, 0);
                if (h1) {
                    acc1[nt] = __builtin_amdgcn_mfma_f32_16x16x32_bf16(bh, ah1[k0], acc1[nt], 0, 0, 0);
                    acc1[nt] = __builtin_amdgcn_mfma_f32_16x16x32_bf16(bl, ah1[k0], acc1[nt], 0, 0, 0);
                    acc1[nt] = __builtin_amdgcn_mfma_f32_16x16x32_bf16(bh, al1[k0], acc1[nt], 0, 0, 0);
                }
            }
        }
    };

    if (TRIPLE) {
        // pass 1: Ps = A@W1 (no bias)
        mmacc();
        {
            float* d0 = out1 + (size_t)r0 * 128 + quad * 4;
            float* d1 = out1 + (size_t)r1 * 128 + quad * 4;
#pragma unroll
            for (int nt = 0; nt < 8; ++nt)
                *(float4*)(d0 + nt * 16) = make_float4(acc0[nt][0], acc0[nt][1], acc0[nt][2], acc0[nt][3]);
            if (h1) {
#pragma unroll
                for (int nt = 0; nt < 8; ++nt)
                    *(float4*)(d1 + nt * 16) = make_float4(acc1[nt][0], acc1[nt][1], acc1[nt][2], acc1[nt][3]);
            }
        }
        // pass 2: Pd = A@W2 + bias2
        __syncthreads();
        copyW(W2h, W2l);
        __syncthreads();
        mmacc();
        {
            float* d0 = out2 + (size_t)r0 * 128 + quad * 4;
            float* d1 = out2 + (size_t)r1 * 128 + quad * 4;
#pragma unroll
            for (int nt = 0; nt < 8; ++nt) {
                float4 bv = *(const float4*)(bias2 + nt * 16 + quad * 4);
                *(float4*)(d0 + nt * 16) = make_float4(acc0[nt][0] + bv.x, acc0[nt][1] + bv.y,
                                                       acc0[nt][2] + bv.z, acc0[nt][3] + bv.w);
                if (h1)
                    *(float4*)(d1 + nt * 16) = make_float4(acc1[nt][0] + bv.x, acc1[nt][1] + bv.y,
                                                           acc1[nt][2] + bv.z, acc1[nt][3] + bv.w);
            }
        }
        // pass 3: tmp = A@W3 + gterm[batch] + bf3
        __syncthreads();
        copyW(W3h, W3l);
        __syncthreads();
        mmacc();
        {
            const float* gp0 = gt + g0 * 128 + quad * 4;
            const float* gp1 = gt + g1 * 128 + quad * 4;
            float* d0 = out3 + (size_t)r0 * 128 + quad * 4;
            float* d1 = out3 + (size_t)r1 * 128 + quad * 4;
#pragma unroll
            for (int nt = 0; nt < 8; ++nt) {
                float4 bv = *(const float4*)(bf3 + nt * 16 + quad * 4);
                float4 gv0 = *(const float4*)(gp0 + nt * 16);
                *(float4*)(d0 + nt * 16) = make_float4(acc0[nt][0] + bv.x + gv0.x, acc0[nt][1] + bv.y + gv0.y,
                                                       acc0[nt][2] + bv.z + gv0.z, acc0[nt][3] + bv.w + gv0.w);
                if (h1) {
                    float4 gv1 = *(const float4*)(gp1 + nt * 16);
                    *(float4*)(d1 + nt * 16) = make_float4(acc1[nt][0] + bv.x + gv1.x, acc1[nt][1] + bv.y + gv1.y,
                                                           acc1[nt][2] + bv.z + gv1.z, acc1[nt][3] + bv.w + gv1.w);
                }
            }
        }
        return;
    }

    // ---- single-pass epilogue ----
    mmacc();
    float4 bc[8];
    if (BIAS) {
#pragma unroll
        for (int nt = 0; nt < 8; ++nt) bc[nt] = *(const float4*)(bias1 + nt * 16 + quad * 4);
    }
    float o0[8][4], o1[8][4];
#pragma unroll
    for (int nt = 0; nt < 8; ++nt)
#pragma unroll
        for (int i = 0; i < 4; ++i) {
            float v0 = acc0[nt][i], v1 = acc1[nt][i];
            if (BIAS) {
                float b = (i == 0) ? bc[nt].x : (i == 1) ? bc[nt].y : (i == 2) ? bc[nt].z : bc[nt].w;
                v0 += b; v1 += b;
            }
            if (ACCUM) {
                float ea = (i == 0) ? e0[nt].x : (i == 1) ? e0[nt].y : (i == 2) ? e0[nt].z : e0[nt].w;
                float eb = (i == 0) ? e1[nt].x : (i == 1) ? e1[nt].y : (i == 2) ? e1[nt].z : e1[nt].w;
                v0 += ea; v1 += eb;
            }
            if (RELU) { v0 = fmaxf(v0, 0.f); v1 = fmaxf(v1, 0.f); }
            o0[nt][i] = v0; o1[nt][i] = v1;
        }
    {
        float* d0 = out1 + (size_t)r0 * 128 + quad * 4;
#pragma unroll
        for (int nt = 0; nt < 8; ++nt)
            *(float4*)(d0 + nt * 16) = make_float4(o0[nt][0], o0[nt][1], o0[nt][2], o0[nt][3]);
    }
    if (h1) {
        float* d1 = out1 + (size_t)r1 * 128 + quad * 4;
#pragma unroll
        for (int nt = 0; nt < 8; ++nt)
            *(float4*)(d1 + nt * 16) = make_float4(o1[nt][0], o1[nt][1], o1[nt][2], o1[nt][3]);
    }
    if (STATS) {
        // tile0
        {
            int glo = __shfl(g0, 0), ghi = __shfl(g0, 15);
            if (glo == ghi) {
#pragma unroll
                for (int nt = 0; nt < 8; ++nt) {
                    float4 v = make_float4(o0[nt][0], o0[nt][1], o0[nt][2], o0[nt][3]);
#pragma unroll
                    for (int off = 1; off < 16; off <<= 1) {
                        v.x += __shfl_xor(v.x, off);
                        v.y += __shfl_xor(v.y, off);
                        v.z += __shfl_xor(v.z, off);
                        v.w += __shfl_xor(v.w, off);
                    }
                    if (m16 == 0) {
                        float* sp = &sum_h[glo * 128 + nt * 16 + quad * 4];
                        atomicAdd(sp + 0, v.x); atomicAdd(sp + 1, v.y);
                        atomicAdd(sp + 2, v.z); atomicAdd(sp + 3, v.w);
                    }
                }
            } else {
#pragma unroll
                for (int nt = 0; nt < 8; ++nt) {
                    float* sp = &sum_h[g0 * 128 + nt * 16 + quad * 4];
                    atomicAdd(sp + 0, o0[nt][0]); atomicAdd(sp + 1, o0[nt][1]);
                    atomicAdd(sp + 2, o0[nt][2]); atomicAdd(sp + 3, o0[nt][3]);
                }
            }
        }
        if (h1) {
            int glo = __shfl(g1, 0), ghi = __shfl(g1, 15);
            if (glo == ghi) {
#pragma unroll
                for (int nt = 0; nt < 8; ++nt) {
                    float4 v = make_float4(o1[nt][0], o1[nt][1], o1[nt][2], o1[nt][3]);
#pragma unroll
                    for (int off = 1; off < 16; off <<= 1) {
                        v.x += __shfl_xor(v.x, off);
                        v.y += __shfl_xor(v.y, off);
                        v.z += __shfl_xor(v.z, off);
                        v.w += __shfl_xor(v.w, off);
                    }
                    if (m16 == 0) {
                        float* sp = &sum_h[glo * 128 + nt * 16 + quad * 4];
                        atomicAdd(sp + 0, v.x); atomicAdd(sp + 1, v.y);
                        atomicAdd(sp + 2, v.z); atomicAdd(sp + 3, v.w);
                    }
                }
            } else {
#pragma unroll
                for (int nt = 0; nt < 8; ++nt) {
                    float* sp = &sum_h[g1 * 128 + nt * 16 + quad * 4];
                    atomicAdd(sp + 0, o1[nt][0]); atomicAdd(sp + 1, o1[nt][1]);
                    atomicAdd(sp + 2, o1[nt][2]); atomicAdd(sp + 3, o1[nt][3]);
                }
            }
        }
    }
}

// ---------------- edge aggregation: one wave per destination node ----------------
__global__ __launch_bounds__(256) void k_edge_agg(const float* __restrict__ Ps, const float* __restrict__ Pd,
                                                  const int* __restrict__ row_ptr, const int* __restrict__ src_sorted,
                                                  const float4* __restrict__ ea_s, const float* __restrict__ Wm1,
                                                  float* __restrict__ accm) {
    const int lane = threadIdx.x & 63;
    const int d = blockIdx.x * 4 + (threadIdx.x >> 6);
    const int c = lane * 2;
    const float2 w0 = *(const float2*)&Wm1[256 * 128 + c];
    const float2 w1 = *(const float2*)&Wm1[257 * 128 + c];
    const float2 w2 = *(const float2*)&Wm1[258 * 128 + c];
    const float2 pd = *(const float2*)&Pd[(size_t)d * 128 + c];
    const int beg = row_ptr[d], end = row_ptr[d + 1];
    const float2 sv = *(const float2*)&Ps[(size_t)d * 128 + c];
    float ax = fmaxf(sv.x + pd.x, 0.f);
    float ay = fmaxf(sv.y + pd.y, 0.f);
    int k = beg;
    for (; k + 3 < end; k += 4) {
        int s0 = src_sorted[k], s1 = src_sorted[k + 1], s2 = src_sorted[k + 2], s3 = src_sorted[k + 3];
        float4 e0 = ea_s[k], e1 = ea_s[k + 1], e2 = ea_s[k + 2], e3 = ea_s[k + 3];
        float2 pa = *(const float2*)&Ps[(size_t)s0 * 128 + c];
        float2 pb = *(const float2*)&Ps[(size_t)s1 * 128 + c];
        float2 pc = *(const float2*)&Ps[(size_t)s2 * 128 + c];
        float2 pe = *(const float2*)&Ps[(size_t)s3 * 128 + c];
        ax += fmaxf(pa.x + pd.x + e0.x * w0.x + e0.y * w1.x + e0.z * w2.x, 0.f)
            + fmaxf(pb.x + pd.x + e1.x * w0.x + e1.y * w1.x + e1.z * w2.x, 0.f)
            + fmaxf(pc.x + pd.x + e2.x * w0.x + e2.y * w1.x + e2.z * w2.x, 0.f)
            + fmaxf(pe.x + pd.x + e3.x * w0.x + e3.y * w1.x + e3.z * w2.x, 0.f);
        ay += fmaxf(pa.y + pd.y + e0.x * w0.y + e0.y * w1.y + e0.z * w2.y, 0.f)
            + fmaxf(pb.y + pd.y + e1.x * w0.y + e1.y * w1.y + e1.z * w2.y, 0.f)
            + fmaxf(pc.y + pd.y + e2.x * w0.y + e2.y * w1.y + e2.z * w2.y, 0.f)
            + fmaxf(pe.y + pd.y + e3.x * w0.y + e3.y * w1.y + e3.z * w2.y, 0.f);
    }
    for (; k < end; ++k) {
        int s0 = src_sorted[k];
        float4 e0 = ea_s[k];
        float2 pa = *(const float2*)&Ps[(size_t)s0 * 128 + c];
        ax += fmaxf(pa.x + pd.x + e0.x * w0.x + e0.y * w1.x + e0.z * w2.x, 0.f);
        ay += fmaxf(pa.y + pd.y + e0.x * w0.y + e0.y * w1.y + e0.z * w2.y, 0.f);
    }
    float inv = 1.f / (float)(end - beg + 1);
    *(float2*)&accm[(size_t)d * 128 + c] = make_float2(ax * inv, ay * inv);
}

// ---------------- encoder per-graph stats (once) ----------------
__global__ __launch_bounds__(256) void k_stats_bc(const float* __restrict__ h, const float* __restrict__ xm,
                                                  const int* __restrict__ batch, float* __restrict__ sum_h,
                                                  float* __restrict__ sum_hbc, float* __restrict__ cnt_node,
                                                  float* __restrict__ cnt_bc) {
    __shared__ float sred[8][128];
    __shared__ float scn[8], scb[8];
    const int t = threadIdx.x;
    const int c4 = (t & 31) * 4;
    const int rsub = t >> 5;   // 0..7
    const int row0 = blockIdx.x * 64;
    int rlo = (row0 < NN) ? row0 : (NN - 1);
    int rhi = (row0 + 63 < NN) ? row0 + 63 : (NN - 1);
    const int gl = batch[rlo];
    const bool uni = (gl == batch[rhi]);
    float4 s = make_float4(0.f, 0.f, 0.f, 0.f), sb = make_float4(0.f, 0.f, 0.f, 0.f);
    float cn = 0.f, cb = 0.f;
#pragma unroll
    for (int ii = 0; ii < 8; ++ii) {
        int r = row0 + ii * 8 + rsub;
        if (r >= NN) continue;
        float4 v = *(const float4*)(h + (size_t)r * 128 + c4);
        float bc = xm[r * 3 + 2];
        if (uni) {
            s.x += v.x; s.y += v.y; s.z += v.z; s.w += v.w;
            sb.x += v.x * bc; sb.y += v.y * bc; sb.z += v.z * bc; sb.w += v.w * bc;
            if ((t & 31) == 0) { cn += 1.f; cb += bc; }
        } else {
            int g = batch[r];
            atomicAdd(&sum_h[g * 128 + c4 + 0], v.x);
            atomicAdd(&sum_h[g * 128 + c4 + 1], v.y);
            atomicAdd(&sum_h[g * 128 + c4 + 2], v.z);
            atomicAdd(&sum_h[g * 128 + c4 + 3], v.w);
            atomicAdd(&sum_hbc[g * 128 + c4 + 0], v.x * bc);
            atomicAdd(&sum_hbc[g * 128 + c4 + 1], v.y * bc);
            atomicAdd(&sum_hbc[g * 128 + c4 + 2], v.z * bc);
            atomicAdd(&sum_hbc[g * 128 + c4 + 3], v.w * bc);
            if ((t & 31) == 0) {
                atomicAdd(&cnt_node[g], 1.f);
                atomicAdd(&cnt_bc[g], bc);
            }
        }
    }
    if (!uni) return;
    *(float4*)&sred[rsub][c4] = s;
    __syncthreads();
    if (t < 128) {
        float tot = 0.f;
#pragma unroll
        for (int q = 0; q < 8; ++q) tot += sred[q][t];
        atomicAdd(&sum_h[gl * 128 + t], tot);
    }
    __syncthreads();
    *(float4*)&sred[rsub][c4] = sb;
    if ((t & 31) == 0) { scn[rsub] = cn; scb[rsub] = cb; }
    __syncthreads();
    if (t < 128) {
        float tot = 0.f;
#pragma unroll
        for (int q = 0; q < 8; ++q) tot += sred[q][t];
        atomicAdd(&sum_hbc[gl * 128 + t], tot);
    }
    if (t == 0) {
        float a = 0.f, b = 0.f;
#pragma unroll
        for (int q = 0; q < 8; ++q) { a += scn[q]; b += scb[q]; }
        atomicAdd(&cnt_node[gl], a);
        atomicAdd(&cnt_bc[gl], b);
    }
}

// gterm[g] = mean_h[g] @ Wu1[256:384] + mean_hbc[g] @ Wu1[384:512]
__global__ __launch_bounds__(128) void k_gterm(const float* __restrict__ sum_h, const float* __restrict__ sum_hbc,
                                               const float* __restrict__ cnt_node, const float* __restrict__ cnt_bc,
                                               const float* __restrict__ Wu1, float* __restrict__ gt) {
    const int g = blockIdx.x;
    const int c = threadIdx.x;
    __shared__ float sg[128], sb[128];
    const float invn = 1.f / fmaxf(cnt_node[g], 1.f);
    const float invb = 1.f / fmaxf(cnt_bc[g], 1.f);
    sg[c] = sum_h[g * 128 + c] * invn;
    sb[c] = sum_hbc[g * 128 + c] * invb;
    __syncthreads();
    float s = 0.f;
    for (int k = 0; k < 128; ++k) s += sg[k] * Wu1[(256 + k) * 128 + c];
    for (int k = 0; k < 128; ++k) s += sb[k] * Wu1[(384 + k) * 128 + c];
    gt[g * 128 + c] = s;
}

// ---------------- decoder layer 2 (128 -> 3), one wave per row ----------------
__global__ __launch_bounds__(256) void k_dec2(const float* __restrict__ t, const float* __restrict__ Wd2,
                                              const float* __restrict__ bd2, float* __restrict__ out, int n) {
    const int lane = threadIdx.x & 63;
    const int r = blockIdx.x * 4 + (threadIdx.x >> 6);
    if (r >= n) return;
    float p0 = 0.f, p1 = 0.f, p2 = 0.f;
    for (int k = lane; k < 128; k += 64) {
        float tv = t[(size_t)r * 128 + k];
        p0 += tv * Wd2[k * 3 + 0];
        p1 += tv * Wd2[k * 3 + 1];
        p2 += tv * Wd2[k * 3 + 2];
    }
    for (int off = 32; off; off >>= 1) {
        p0 += __shfl_down(p0, off);
        p1 += __shfl_down(p1, off);
        p2 += __shfl_down(p2, off);
    }
    if (lane == 0) {
        out[r * 3 + 0] = p0 + bd2[0];
        out[r * 3 + 1] = p1 + bd2[1];
        out[r * 3 + 2] = p2 + bd2[2];
    }
}

extern "C" void kernel_launch(void* const* d_in, const int* in_sizes, int n_in,
                              void* d_out, int out_size, void* d_ws, size_t ws_size,
                              hipStream_t stream) {
    const float* x = (const float*)d_in[0];
    const float* x_mask = (const float*)d_in[1];
    const float* edge_attr = (const float*)d_in[2];
    const float* W_e1 = (const float*)d_in[4];
    const float* b_e1 = (const float*)d_in[5];
    const float* W_e2 = (const float*)d_in[6];
    const float* b_e2 = (const float*)d_in[7];
    const float* W_m1 = (const float*)d_in[8];
    const float* b_m1 = (const float*)d_in[9];
    const float* W_m2 = (const float*)d_in[10];
    const float* b_m2 = (const float*)d_in[11];
    const float* W_u1 = (const float*)d_in[12];
    const float* b_u1 = (const float*)d_in[13];
    const float* W_u2 = (const float*)d_in[14];
    const float* b_u2 = (const float*)d_in[15];
    const float* W_d1 = (const float*)d_in[16];
    const float* b_d1 = (const float*)d_in[17];
    const float* W_d2 = (const float*)d_in[18];
    const float* b_d2 = (const float*)d_in[19];
    const int* edge_index = (const int*)d_in[20];
    const int* batch = (const int*)d_in[21];
    float* out = (float*)d_out;

    char* wp = (char*)d_ws;
    auto carve = [&](size_t bytes) {
        char* r = wp;
        wp += (bytes + 255) & ~(size_t)255;
        return r;
    };
    float* h = (float*)carve(sizeof(float) * (size_t)NN * 128);
    float* Ps = (float*)carve(sizeof(float) * (size_t)NN * 128);
    float* Pd = (float*)carve(sizeof(float) * (size_t)NN * 128);
    float* accm = (float*)carve(sizeof(float) * (size_t)NN * 128);
    float* tmpb = (float*)carve(sizeof(float) * (size_t)NN * 128);
    float4* ea_s = (float4*)carve(sizeof(float4) * (size_t)EE);
    float* stats = (float*)carve(sizeof(float) * 4096);
    float* sum_h = stats;             // 1024
    float* sum_hbc = stats + 1024;    // 1024
    float* cnt_node = stats + 2048;   // 8
    float* cnt_bc = stats + 2056;     // 8
    float* gterm = stats + 2304;      // 1024
    float* bfused = stats + 3328;     // 128
    int* deg = (int*)carve(sizeof(int) * NN);
    int* row_ptr = (int*)carve(sizeof(int) * (NN + 1));
    int* cursor = (int*)carve(sizeof(int) * NN);
    int* src_sorted = (int*)carve(sizeof(int) * EE);
    int* exbuf = (int*)carve(sizeof(int) * NN);
    int* blksum = (int*)carve(sizeof(int) * 256);
    float* Wf = (float*)carve(sizeof(float) * 16384);
    short* We2h = (short*)carve(sizeof(short) * 16384);
    short* We2l = (short*)carve(sizeof(short) * 16384);
    short* Wm1sh = (short*)carve(sizeof(short) * 16384);
    short* Wm1sl = (short*)carve(sizeof(short) * 16384);
    short* Wm1dh = (short*)carve(sizeof(short) * 16384);
    short* Wm1dl = (short*)carve(sizeof(short) * 16384);
    short* Wu1ah = (short*)carve(sizeof(short) * 16384);
    short* Wu1al = (short*)carve(sizeof(short) * 16384);
    short* Wfh = (short*)carve(sizeof(short) * 16384);
    short* Wfl = (short*)carve(sizeof(short) * 16384);
    short* Wu2h = (short*)carve(sizeof(short) * 16384);
    short* Wu2l = (short*)carve(sizeof(short) * 16384);
    short* Wd1h = (short*)carve(sizeof(short) * 16384);
    short* Wd1l = (short*)carve(sizeof(short) * 16384);

    const dim3 b256(256);
    const int gE256 = (EE + 255) / 256;

    hipMemsetAsync(deg, 0, sizeof(int) * NN, stream);
    hipMemsetAsync(stats, 0, sizeof(float) * 2064, stream);
    k_wfuse<<<64, b256, 0, stream>>>(W_m2, W_u1, Wf);
    k_bfuse<<<1, 128, 0, stream>>>(b_m2, W_u1, b_u1, bfused);
    k_pack_all<<<448, b256, 0, stream>>>(W_e2, W_m1, W_u1, Wf, W_u2, W_d1,
                                         We2h, We2l, Wm1sh, Wm1sl, Wm1dh, Wm1dl,
                                         Wu1ah, Wu1al, Wfh, Wfl, Wu2h, Wu2l, Wd1h, Wd1l);
    // CSR
    k_count<<<gE256, b256, 0, stream>>>(edge_index, deg);
    k_scan1<<<NBLK, b256, 0, stream>>>(deg, exbuf, blksum);
    k_scan2<<<1, b256, 0, stream>>>(blksum);
    k_scan3<<<NBLK, b256, 0, stream>>>(exbuf, blksum, row_ptr, cursor);
    k_scatter<<<gE256, b256, 0, stream>>>(edge_index, edge_attr, cursor, src_sorted, ea_s);
    // encoder
    k_enc1<<<(NN + 31) / 32, b256, 0, stream>>>(x, x_mask, W_e1, b_e1, accm, NN);
    sgemm<false, false, true, false, false><<<SGRID, b256, 0, stream>>>(
        accm, We2h, We2l, nullptr, nullptr, nullptr, nullptr, b_e2, nullptr,
        nullptr, nullptr, nullptr, h, nullptr, nullptr, nullptr, NN);
    k_stats_bc<<<(NN + 63) / 64, b256, 0, stream>>>(h, x_mask, batch, sum_h, sum_hbc, cnt_node, cnt_bc);

    for (int rep = 0; rep < 3; ++rep) {
        k_gterm<<<GG, 128, 0, stream>>>(sum_h, sum_hbc, cnt_node, cnt_bc, W_u1, gterm);
        // TRIPLE: Ps = h@Wm1s ; Pd = h@Wm1d + bm1 ; tmp = h@Wu1a + gterm[batch] + bfused
        sgemm<false, false, false, false, true><<<SGRID, b256, 0, stream>>>(
            h, Wm1sh, Wm1sl, Wm1dh, Wm1dl, Wu1ah, Wu1al, nullptr, b_m1,
            gterm, bfused, batch, Ps, Pd, tmpb, nullptr, NN);
        k_edge_agg<<<NN / 4, b256, 0, stream>>>(Ps, Pd, row_ptr, src_sorted, ea_s, W_m1, accm);
        // pre = relu(tmp + accm@Wf)  (in place into tmpb)
        sgemm<true, true, false, false, false><<<SGRID, b256, 0, stream>>>(
            accm, Wfh, Wfl, nullptr, nullptr, nullptr, nullptr, nullptr, nullptr,
            nullptr, nullptr, nullptr, tmpb, nullptr, nullptr, nullptr, NN);
        // h += pre@Wu2 + bu2 (+stats for next rep)
        if (rep < 2) {
            hipMemsetAsync(sum_h, 0, sizeof(float) * 1024, stream);
            sgemm<false, true, true, true, false><<<SGRID, b256, 0, stream>>>(
                tmpb, Wu2h, Wu2l, nullptr, nullptr, nullptr, nullptr, b_u2, nullptr,
                nullptr, nullptr, batch, h, nullptr, nullptr, sum_h, NN);
        } else {
            sgemm<false, true, true, false, false><<<SGRID, b256, 0, stream>>>(
                tmpb, Wu2h, Wu2l, nullptr, nullptr, nullptr, nullptr, b_u2, nullptr,
                nullptr, nullptr, nullptr, h, nullptr, nullptr, nullptr, NN);
        }
    }
    // decoder
    sgemm<true, false, true, false, false><<<SGRID, b256, 0, stream>>>(
        h, Wd1h, Wd1l, nullptr, nullptr, nullptr, nullptr, b_d1, nullptr,
        nullptr, nullptr, nullptr, accm, nullptr, nullptr, nullptr, NN);
    k_dec2<<<NN / 4, b256, 0, stream>>>(accm, W_d2, b_d2, out, NN);
}